// Round 4
// baseline (246.021 us; speedup 1.0000x reference)
//
#include <hip/hip_runtime.h>

// SelfAttention_33852932227207 — MI355X, round 4.
// e = x^T (Wq^T Wa Wk) x / sqrt(512);  out = softmax(e) @ (x (Wb Wv)^T).
// Round-4 k_attn restructure:
//  * 4-wave blocks, BQ=16, grid 512 -> 2 independent blocks/CU (barrier overlap)
//  * P tile in LDS (16KB, XOR-swizzled) -> invariants no longer spill to
//    in-loop global reloads (r3: VGPR=112 < 192 resident set was the stall)
//  * wave w: scores for key-group w (no K redundancy) + PV d-slice w*128..+128
//  * single ureg buffer (PV consumes, then next U issues into same regs)
//  * fixed-max softmax, 1 lgkm-only barrier/kt, K/U loads fly across barriers

typedef __attribute__((ext_vector_type(8))) short b16x8;
typedef __attribute__((ext_vector_type(4))) float f4;
typedef unsigned short u16;

#define DEVINL __device__ __forceinline__

DEVINL u16 f2bf(float f) {               // fp32 -> bf16 RNE
  unsigned int u = __float_as_uint(f);
  u = u + 0x7FFFu + ((u >> 16) & 1u);
  return (u16)(u >> 16);
}
DEVINL float bf2f(u16 h) { return __uint_as_float(((unsigned int)h) << 16); }

DEVINL f4 mfma_(b16x8 a, b16x8 b, f4 c) {
  return __builtin_amdgcn_mfma_f32_16x16x32_bf16(a, b, c, 0, 0, 0);
}
DEVINL b16x8 pack8(ushort4 a, ushort4 b) {
  b16x8 v = {(short)a.x, (short)a.y, (short)a.z, (short)a.w,
             (short)b.x, (short)b.y, (short)b.z, (short)b.w};
  return v;
}
DEVINL void gload16(const u16* g, u16* l) {
  __builtin_amdgcn_global_load_lds(
      (const __attribute__((address_space(1))) void*)g,
      (__attribute__((address_space(3))) void*)l, 16, 0, 0);
}

// barrier that does NOT drain vmcnt: LDS writes flushed (lgkmcnt), global
// loads to registers stay in flight. Cross-wave data goes through LDS only.
#define BARRIER_LDS()                                      \
  do {                                                     \
    asm volatile("s_waitcnt lgkmcnt(0)" ::: "memory");     \
    __builtin_amdgcn_s_barrier();                          \
    asm volatile("" ::: "memory");                         \
  } while (0)

// ---------------------------------------------------------------------------
// K0: x [8192][1024] fp32 -> bf16
__global__ __launch_bounds__(256) void k_split_x(const float* __restrict__ x,
                                                 u16* __restrict__ xh) {
  int i = blockIdx.x * 256 + threadIdx.x;
  float4 v = ((const float4*)x)[i];
  ushort4 h;
  h.x = f2bf(v.x); h.y = f2bf(v.y); h.z = f2bf(v.z); h.w = f2bf(v.w);
  ((ushort4*)xh)[i] = h;
}

// ---------------------------------------------------------------------------
// K1: fold weights (fp32 accumulate) into Wcat [1536][1024] bf16.
//   rows 0..511 = Wk ; 512..1023 = Wa^T Wq ; 1024..1535 = Wb Wv
__global__ __launch_bounds__(256) void k_fold(const float* __restrict__ Wk,
                                              const float* __restrict__ Wq,
                                              const float* __restrict__ Wv,
                                              const float* __restrict__ Wa,
                                              const float* __restrict__ Wb,
                                              u16* __restrict__ wh) {
  int bid = blockIdx.x, t = threadIdx.x;
  if (bid < 512) {
    int i = bid * 256 + t;
    float4 v = ((const float4*)Wk)[i];
    ushort4 h;
    h.x = f2bf(v.x); h.y = f2bf(v.y); h.z = f2bf(v.z); h.w = f2bf(v.w);
    ((ushort4*)wh)[i] = h;
  } else if (bid < 768) {
    int blk = bid - 512;
    int r0 = (blk >> 2) * 8;
    int c = (blk & 3) * 256 + t;
    float acc[8] = {0.f, 0.f, 0.f, 0.f, 0.f, 0.f, 0.f, 0.f};
#pragma unroll 4
    for (int m = 0; m < 512; ++m) {
      float wq = Wq[m * 1024 + c];
#pragma unroll
      for (int i = 0; i < 8; ++i) acc[i] = __fmaf_rn(Wa[m * 512 + r0 + i], wq, acc[i]);
    }
#pragma unroll
    for (int i = 0; i < 8; ++i) wh[(512 + r0 + i) * 1024 + c] = f2bf(acc[i]);
  } else {
    int blk = bid - 768;
    int r0 = (blk >> 2) * 8;
    int c = (blk & 3) * 256 + t;
    float acc[8] = {0.f, 0.f, 0.f, 0.f, 0.f, 0.f, 0.f, 0.f};
#pragma unroll 4
    for (int m = 0; m < 512; ++m) {
      float wv = Wv[m * 1024 + c];
#pragma unroll
      for (int i = 0; i < 8; ++i) acc[i] = __fmaf_rn(Wb[(r0 + i) * 512 + m], wv, acc[i]);
    }
#pragma unroll
    for (int i = 0; i < 8; ++i) wh[(1024 + r0 + i) * 1024 + c] = f2bf(acc[i]);
  }
}

// ---------------------------------------------------------------------------
// K2: projection GEMM  Y[8192][1536] = x[8192][1024] @ Wcat^T, bf16.
// 128x128 tile, BK=32, 4 waves, global_load_lds staging (m97 structure).
__global__ __launch_bounds__(256) void k_proj(
    const u16* __restrict__ xh, const u16* __restrict__ wh,
    u16* __restrict__ kh, u16* __restrict__ ph, u16* __restrict__ uh) {
  __shared__ u16 lxh[4096], lwh[4096];  // [128][32] each
  const int cb = blockIdx.x;   // 0..11 column block
  const int rb = blockIdx.y;   // 0..63 row block
  const int t = threadIdx.x, lane = t & 63, w = t >> 6;
  const int wr = w >> 1, wc = w & 1, ql = lane & 15, g = lane >> 4;
  const f4 fzero = {0.f, 0.f, 0.f, 0.f};
  f4 acc[4][4];
#pragma unroll
  for (int i = 0; i < 4; ++i)
#pragma unroll
    for (int j = 0; j < 4; ++j) acc[i][j] = fzero;

  const int c0 = w * 64 + lane;
  for (int ks = 0; ks < 32; ++ks) {
    __syncthreads();
#pragma unroll
    for (int r = 0; r < 2; ++r) {
      int c = r * 256 + c0;                  // 0..511, wave-contiguous
      int row = c >> 2, fo = (c & 3) * 8;
      gload16(&xh[(rb * 128 + row) * 1024 + ks * 32 + fo], &lxh[c * 8]);
      gload16(&wh[(cb * 128 + row) * 1024 + ks * 32 + fo], &lwh[c * 8]);
    }
    __syncthreads();
    b16x8 ah[4], bh[4];
#pragma unroll
    for (int rt = 0; rt < 4; ++rt)
      ah[rt] = *(const b16x8*)&lxh[(wr * 64 + rt * 16 + ql) * 32 + g * 8];
#pragma unroll
    for (int ct = 0; ct < 4; ++ct)
      bh[ct] = *(const b16x8*)&lwh[(wc * 64 + ct * 16 + ql) * 32 + g * 8];
#pragma unroll
    for (int rt = 0; rt < 4; ++rt)
#pragma unroll
      for (int ct = 0; ct < 4; ++ct)
        acc[rt][ct] = mfma_(ah[rt], bh[ct], acc[rt][ct]);
  }

  // epilogue: C frag layout col=lane&15, row=(lane>>4)*4+reg
#pragma unroll
  for (int rt = 0; rt < 4; ++rt) {
#pragma unroll
    for (int ct = 0; ct < 4; ++ct) {
      f4 v = acc[rt][ct];
      int col = cb * 128 + wc * 64 + ct * 16 + ql;
      int rowb = rb * 128 + wr * 64 + rt * 16 + g * 4;
      if (cb < 4) {
#pragma unroll
        for (int r = 0; r < 4; ++r) kh[(rowb + r) * 512 + col] = f2bf(v[r]);
      } else if (cb < 8) {
        int c2 = col - 512;
#pragma unroll
        for (int r = 0; r < 4; ++r) ph[(rowb + r) * 512 + c2] = f2bf(v[r]);
      } else {
        // U pre-swizzled for PV A-operand
        int tt = (cb - 8) * 8 + wc * 4 + ct;
        int rbase = rb * 128 + wr * 64 + rt * 16;
        int j = rbase >> 5, half = (rbase >> 4) & 1;
        ushort4 hh;
        hh.x = f2bf(v[0]); hh.y = f2bf(v[1]); hh.z = f2bf(v[2]); hh.w = f2bf(v[3]);
        *(ushort4*)&uh[((j * 32 + tt) * 64 + lane) * 8 + half * 4] = hh;
      }
    }
  }
}

// ---------------------------------------------------------------------------
// K3: flash attention, fixed-max softmax, 4 waves/block, BQ=16, KVBLK=64.
// Grid 512 (2 blocks/CU). Wave w: QK for key-group w (16 keys x 16 q, full
// Kdim 512) + PV d-slice [w*128, w*128+128). P invariant in swizzled LDS.
__global__ __launch_bounds__(256, 2) void k_attn(
    const u16* __restrict__ kh, const u16* __restrict__ ph,
    const u16* __restrict__ uh, float* __restrict__ out) {
  constexpr float INVT = 0.04419417382415922f;  // 1/sqrt(512)
  __shared__ uint4 pLDS[1024];                  // P tile 16q x 512d, swizzled
  __shared__ u16 sprob[2][16][72];              // [buf][q][key] pad 72
  __shared__ float reds[4][16];
  const int blk = blockIdx.x;
  const int xcd = blk & 7, slot = blk >> 3;
  const int b = xcd >> 1, qb = slot * 2 + (xcd & 1);   // bijective over 512
  const int q0 = qb * 16;
  const int t = threadIdx.x, lane = t & 63, w = t >> 6;
  const int ql = lane & 15, g = lane >> 4;
  const int qswz = ql & 7;
  const f4 fzero = {0.f, 0.f, 0.f, 0.f};

  // ---- stage P[q0..q0+16) x 512 into LDS, swizzled: slot ^= (q&7)
#pragma unroll
  for (int i = 0; i < 4; ++i) {
    int s = i * 256 + t;                 // 16B slot, 1024 total
    int q = s >> 6;
    uint4 v = *(const uint4*)&ph[(b * 2048 + q0 + q) * 512 + (s & 63) * 8];
    pLDS[s ^ (q & 7)] = v;
  }

  f4 acc[8];
#pragma unroll
  for (int i = 0; i < 8; ++i) acc[i] = fzero;
  float llocal = 0.f;

  // K rows for this wave: keys kt*64 + w*16 + ql
  const int arow0 = (b * 2048 + w * 16 + ql) * 512;
  b16x8 kreg[16];
#pragma unroll
  for (int ks = 0; ks < 16; ++ks)
    kreg[ks] = *(const b16x8*)&kh[arow0 + ks * 32 + g * 8];

  b16x8 ureg[16];
  const u16* ub0 = uh + ((size_t)((b * 64) * 32 + w * 8) * 64 + lane) * 8;

  __syncthreads();   // P staged

  for (int kt = 0; kt < 32; ++kt) {
    const int cur = kt & 1;
    // ---- QK(kt): 16 MFMAs, A=kreg, B=P from swizzled LDS
    f4 s0 = fzero, s1 = fzero;
    __builtin_amdgcn_s_setprio(1);
#pragma unroll
    for (int ks = 0; ks < 16; ks += 2) {
      b16x8 pf0 = *(const b16x8*)&pLDS[(ql * 64 + ks * 4 + g) ^ qswz];
      b16x8 pf1 = *(const b16x8*)&pLDS[(ql * 64 + ks * 4 + 4 + g) ^ qswz];
      s0 = mfma_(kreg[ks], pf0, s0);
      s1 = mfma_(kreg[ks + 1], pf1, s1);
    }
    __builtin_amdgcn_s_setprio(0);
    // ---- prefetch K(kt+1) (kreg consumed; loads fly across the barrier)
    if (kt < 31) {
      const u16* kp = &kh[arow0 + (kt + 1) * 64 * 512];
#pragma unroll
      for (int ks = 0; ks < 16; ++ks)
        kreg[ks] = *(const b16x8*)&kp[ks * 32 + g * 8];
    }
    // ---- probs (fixed max = 0): keys kt*64 + w*16 + g*4 + r, query q0+ql
    float p0 = __expf((s0[0] + s1[0]) * INVT);
    float p1 = __expf((s0[1] + s1[1]) * INVT);
    float p2 = __expf((s0[2] + s1[2]) * INVT);
    float p3 = __expf((s0[3] + s1[3]) * INVT);
    llocal += (p0 + p1) + (p2 + p3);
    ushort4 hh;
    hh.x = f2bf(p0); hh.y = f2bf(p1); hh.z = f2bf(p2); hh.w = f2bf(p3);
    *(ushort4*)&sprob[cur][ql][w * 16 + g * 4] = hh;
    // ---- PV(kt-1): consume ureg + sprob[cur^1]
    if (kt > 0) {
      __builtin_amdgcn_s_setprio(1);
#pragma unroll
      for (int j = 0; j < 2; ++j) {
        ushort4 x0 = *(const ushort4*)&sprob[cur ^ 1][ql][j * 32 + g * 4];
        ushort4 x1 = *(const ushort4*)&sprob[cur ^ 1][ql][j * 32 + 16 + g * 4];
        b16x8 pb = pack8(x0, x1);
#pragma unroll
        for (int dt = 0; dt < 8; ++dt)
          acc[dt] = mfma_(ureg[j * 8 + dt], pb, acc[dt]);
      }
      __builtin_amdgcn_s_setprio(0);
    }
    // ---- issue U(kt) into ureg (just consumed; used next iteration)
    {
      const u16* up = ub0 + (size_t)(kt * 2) * 32 * 64 * 8;
#pragma unroll
      for (int j = 0; j < 2; ++j)
#pragma unroll
        for (int dt = 0; dt < 8; ++dt)
          ureg[j * 8 + dt] = *(const b16x8*)&up[((size_t)j * 32 + dt) * 512];
    }
    BARRIER_LDS();
  }
  // ---- PV(31)
  {
#pragma unroll
    for (int j = 0; j < 2; ++j) {
      ushort4 x0 = *(const ushort4*)&sprob[1][ql][j * 32 + g * 4];
      ushort4 x1 = *(const ushort4*)&sprob[1][ql][j * 32 + 16 + g * 4];
      b16x8 pb = pack8(x0, x1);
#pragma unroll
      for (int dt = 0; dt < 8; ++dt)
        acc[dt] = mfma_(ureg[j * 8 + dt], pb, acc[dt]);
    }
  }
  // ---- final l reduce: over g within wave, over waves via LDS
  llocal += __shfl_xor(llocal, 16);
  llocal += __shfl_xor(llocal, 32);
  if (lane < 16) reds[w][lane] = llocal;
  __syncthreads();
  float l = (reds[0][ql] + reds[1][ql]) + (reds[2][ql] + reds[3][ql]);
  float inv = 1.0f / l;
  // ---- store: acc[dt][r] = out[q0+ql][w*128 + dt*16 + g*4 + r]
  const int orow = (b * 2048 + q0 + ql) * 512;
#pragma unroll
  for (int dt = 0; dt < 8; ++dt) {
    f4 v = acc[dt] * inv;
    *(f4*)&out[orow + w * 128 + dt * 16 + g * 4] = v;
  }
}

// ---------------------------------------------------------------------------
extern "C" void kernel_launch(void* const* d_in, const int* in_sizes, int n_in,
                              void* d_out, int out_size, void* d_ws, size_t ws_size,
                              hipStream_t stream) {
  const float* x = (const float*)d_in[0];
  const float* Wk = (const float*)d_in[1];
  const float* Wq = (const float*)d_in[2];
  const float* Wv = (const float*)d_in[3];
  const float* Wa = (const float*)d_in[4];
  const float* Wb = (const float*)d_in[5];
  float* out = (float*)d_out;

  char* ws = (char*)d_ws;
  size_t off = 0;
  auto alloc = [&](size_t bytes) -> void* {
    void* p = ws + off;
    off += (bytes + 255) & ~(size_t)255;
    return p;
  };
  u16* wh = (u16*)alloc(1536 * 1024 * 2);
  u16* xh = (u16*)alloc(8192 * 1024 * 2);
  u16* kh = (u16*)alloc(8192 * 512 * 2);
  u16* ph = (u16*)alloc(8192 * 512 * 2);
  u16* uh = (u16*)alloc(8192 * 512 * 2);
  (void)ws_size; (void)in_sizes; (void)n_in; (void)out_size;

  hipLaunchKernelGGL(k_split_x, dim3(8192), dim3(256), 0, stream, x, xh);
  hipLaunchKernelGGL(k_fold, dim3(1024), dim3(256), 0, stream, Wk, Wq, Wv, Wa, Wb, wh);
  hipLaunchKernelGGL(k_proj, dim3(12, 64), dim3(256), 0, stream, xh, wh, kh, ph, uh);
  hipLaunchKernelGGL(k_attn, dim3(512), dim3(256), 0, stream, kh, ph, uh, out);
}

// Round 5
// 162.592 us; speedup vs baseline: 1.5131x; 1.5131x over previous
//
#include <hip/hip_runtime.h>

// SelfAttention_33852932227207 — MI355X, round 5.
// e = x^T (Wq^T Wa Wk) x / sqrt(512);  out = softmax(e) @ (x (Wb Wv)^T).
// Round-5: attention = two plain GEMMs (fixed-max softmax makes exp a pure
// epilogue). k_score: E=P@K^T -> probs=exp(E/T) bf16 + atomic row sums l.
// k_out: outT = ut @ probs^T (both row-major in k), epilogue /l[q].
// All GEMMs: m97 structure (128^2 tile, global_load_lds w16), BK=64,
// XOR-chunk LDS swizzle via pre-swizzled gload source (involution).

typedef __attribute__((ext_vector_type(8))) short b16x8;
typedef __attribute__((ext_vector_type(4))) float f4;
typedef unsigned short u16;

#define DEVINL __device__ __forceinline__

DEVINL u16 f2bf(float f) {               // fp32 -> bf16 RNE
  unsigned int u = __float_as_uint(f);
  u = u + 0x7FFFu + ((u >> 16) & 1u);
  return (u16)(u >> 16);
}
DEVINL float bf2f(u16 h) { return __uint_as_float(((unsigned int)h) << 16); }

DEVINL f4 mfma_(b16x8 a, b16x8 b, f4 c) {
  return __builtin_amdgcn_mfma_f32_16x16x32_bf16(a, b, c, 0, 0, 0);
}
DEVINL void gload16(const u16* g, u16* l) {
  __builtin_amdgcn_global_load_lds(
      (const __attribute__((address_space(1))) void*)g,
      (__attribute__((address_space(3))) void*)l, 16, 0, 0);
}

// ---- shared GEMM tile helpers: [128][64] bf16 tile, 16B-chunk XOR swizzle.
// LDS chunk cp holds global chunk (row = cp>>3, j = (cp&7) ^ (row&7)).
// Read of frag (row, kk, g) -> chunk row*8 + ((kk*4+g) ^ (row&7)): the 16
// ql-lanes spread over 8 chunk-slots => 2-way bank aliasing (free).
DEVINL void stage_tile(const u16* __restrict__ gbase, int rstride,
                       u16* __restrict__ lds, int t) {
#pragma unroll
  for (int r = 0; r < 4; ++r) {
    int cp = r * 256 + t;                // chunk 0..1023
    int row = cp >> 3, j = cp & 7;
    int jj = j ^ (row & 7);
    gload16(&gbase[(size_t)row * rstride + jj * 8], &lds[cp * 8]);
  }
}
DEVINL b16x8 readfrag(const u16* __restrict__ lds, int row, int kk, int g) {
  int chunk = row * 8 + ((kk * 4 + g) ^ (row & 7));
  return *(const b16x8*)&lds[chunk * 8];
}

// ---------------------------------------------------------------------------
// K0: x [8192][1024] fp32 -> bf16
__global__ __launch_bounds__(256) void k_split_x(const float* __restrict__ x,
                                                 u16* __restrict__ xh) {
  int i = blockIdx.x * 256 + threadIdx.x;
  float4 v = ((const float4*)x)[i];
  ushort4 h;
  h.x = f2bf(v.x); h.y = f2bf(v.y); h.z = f2bf(v.z); h.w = f2bf(v.w);
  ((ushort4*)xh)[i] = h;
}

// ---------------------------------------------------------------------------
// K1: fold weights (fp32 accumulate) into Wcat [1536][1024] bf16.
//   rows 0..511 = Wk ; 512..1023 = Wa^T Wq ; 1024..1535 = Wb Wv
__global__ __launch_bounds__(256) void k_fold(const float* __restrict__ Wk,
                                              const float* __restrict__ Wq,
                                              const float* __restrict__ Wv,
                                              const float* __restrict__ Wa,
                                              const float* __restrict__ Wb,
                                              u16* __restrict__ wh) {
  int bid = blockIdx.x, t = threadIdx.x;
  if (bid < 512) {
    int i = bid * 256 + t;
    float4 v = ((const float4*)Wk)[i];
    ushort4 h;
    h.x = f2bf(v.x); h.y = f2bf(v.y); h.z = f2bf(v.z); h.w = f2bf(v.w);
    ((ushort4*)wh)[i] = h;
  } else if (bid < 768) {
    int blk = bid - 512;
    int r0 = (blk >> 2) * 8;
    int c = (blk & 3) * 256 + t;
    float acc[8] = {0.f, 0.f, 0.f, 0.f, 0.f, 0.f, 0.f, 0.f};
#pragma unroll 4
    for (int m = 0; m < 512; ++m) {
      float wq = Wq[m * 1024 + c];
#pragma unroll
      for (int i = 0; i < 8; ++i) acc[i] = __fmaf_rn(Wa[m * 512 + r0 + i], wq, acc[i]);
    }
#pragma unroll
    for (int i = 0; i < 8; ++i) wh[(512 + r0 + i) * 1024 + c] = f2bf(acc[i]);
  } else {
    int blk = bid - 768;
    int r0 = (blk >> 2) * 8;
    int c = (blk & 3) * 256 + t;
    float acc[8] = {0.f, 0.f, 0.f, 0.f, 0.f, 0.f, 0.f, 0.f};
#pragma unroll 4
    for (int m = 0; m < 512; ++m) {
      float wv = Wv[m * 1024 + c];
#pragma unroll
      for (int i = 0; i < 8; ++i) acc[i] = __fmaf_rn(Wb[(r0 + i) * 512 + m], wv, acc[i]);
    }
#pragma unroll
    for (int i = 0; i < 8; ++i) wh[(1024 + r0 + i) * 1024 + c] = f2bf(acc[i]);
  }
}

// ---------------------------------------------------------------------------
// K2: projection GEMM  Y[8192][1536] = x[8192][1024] @ Wcat^T, bf16, BK=64.
// Outputs: cols 0..511 -> K rowmajor [s][512]; 512..1023 -> P rowmajor;
//          1024..1535 -> ut[b][d][k] (U transposed, contiguous ushort4).
__global__ __launch_bounds__(256, 2) void k_proj(
    const u16* __restrict__ xh, const u16* __restrict__ wh,
    u16* __restrict__ kh, u16* __restrict__ ph, u16* __restrict__ ut) {
  __shared__ u16 lxh[8192], lwh[8192];  // [128][64] each
  const int cb = blockIdx.x;   // 0..11 column block
  const int rb = blockIdx.y;   // 0..63 row block
  const int t = threadIdx.x, lane = t & 63, w = t >> 6;
  const int wr = w >> 1, wc = w & 1, ql = lane & 15, g = lane >> 4;
  const f4 fzero = {0.f, 0.f, 0.f, 0.f};
  f4 acc[4][4];
#pragma unroll
  for (int i = 0; i < 4; ++i)
#pragma unroll
    for (int j = 0; j < 4; ++j) acc[i][j] = fzero;

  for (int ks = 0; ks < 16; ++ks) {
    __syncthreads();
    stage_tile(&xh[(size_t)(rb * 128) * 1024 + ks * 64], 1024, lxh, t);
    stage_tile(&wh[(size_t)(cb * 128) * 1024 + ks * 64], 1024, lwh, t);
    __syncthreads();
#pragma unroll
    for (int kk = 0; kk < 2; ++kk) {
      b16x8 ah[4], bh[4];
#pragma unroll
      for (int rt = 0; rt < 4; ++rt)
        ah[rt] = readfrag(lxh, wr * 64 + rt * 16 + ql, kk, g);
#pragma unroll
      for (int ct = 0; ct < 4; ++ct)
        bh[ct] = readfrag(lwh, wc * 64 + ct * 16 + ql, kk, g);
#pragma unroll
      for (int rt = 0; rt < 4; ++rt)
#pragma unroll
        for (int ct = 0; ct < 4; ++ct)
          acc[rt][ct] = mfma_(ah[rt], bh[ct], acc[rt][ct]);
    }
  }

  // epilogue: C frag layout col=lane&15, row=(lane>>4)*4+reg
#pragma unroll
  for (int rt = 0; rt < 4; ++rt) {
#pragma unroll
    for (int ct = 0; ct < 4; ++ct) {
      f4 v = acc[rt][ct];
      int col = cb * 128 + wc * 64 + ct * 16 + ql;
      int rowb = rb * 128 + wr * 64 + rt * 16 + g * 4;
      if (cb < 4) {
#pragma unroll
        for (int r = 0; r < 4; ++r) kh[(size_t)(rowb + r) * 512 + col] = f2bf(v[r]);
      } else if (cb < 8) {
        int c2 = col - 512;
#pragma unroll
        for (int r = 0; r < 4; ++r) ph[(size_t)(rowb + r) * 512 + c2] = f2bf(v[r]);
      } else {
        int d = (cb - 8) * 128 + wc * 64 + ct * 16 + ql;
        int bb = rowb >> 11, k0 = rowb & 2047;
        ushort4 hh;
        hh.x = f2bf(v[0]); hh.y = f2bf(v[1]); hh.z = f2bf(v[2]); hh.w = f2bf(v[3]);
        *(ushort4*)&ut[((size_t)bb * 512 + d) * 2048 + k0] = hh;
      }
    }
  }
}

// ---------------------------------------------------------------------------
// K3: score GEMM. E[q][k] = sum_d P[q][d] K[k][d] per batch; epilogue
// probs = exp(E/T) bf16 + atomicAdd row sums l[b*2048+q].
// Grid 1024: batch -> XCD pair (K+P 4MB fits 2 L2s).
__global__ __launch_bounds__(256, 2) void k_score(
    const u16* __restrict__ ph, const u16* __restrict__ kh,
    u16* __restrict__ probs, float* __restrict__ l) {
  constexpr float INVT = 0.04419417382415922f;  // 1/sqrt(512)
  __shared__ u16 lp[8192], lk[8192];
  const int blk = blockIdx.x;
  const int xcd = blk & 7, half = xcd & 1, b = xcd >> 1;
  const int idx = blk >> 3;                  // 0..127
  const int qtb = idx >> 3;                  // 0..15
  const int ktb = half * 8 + (idx & 7);      // 0..15
  const int q0 = qtb * 128, k0 = ktb * 128;
  const int t = threadIdx.x, lane = t & 63, w = t >> 6;
  const int wr = w >> 1, wc = w & 1, ql = lane & 15, g = lane >> 4;
  const f4 fzero = {0.f, 0.f, 0.f, 0.f};
  f4 acc[4][4];
#pragma unroll
  for (int i = 0; i < 4; ++i)
#pragma unroll
    for (int j = 0; j < 4; ++j) acc[i][j] = fzero;

  for (int ks = 0; ks < 8; ++ks) {           // Kd = 512
    __syncthreads();
    stage_tile(&ph[((size_t)b * 2048 + q0) * 512 + ks * 64], 512, lp, t);
    stage_tile(&kh[((size_t)b * 2048 + k0) * 512 + ks * 64], 512, lk, t);
    __syncthreads();
#pragma unroll
    for (int kk = 0; kk < 2; ++kk) {
      b16x8 ah[4], bh[4];
#pragma unroll
      for (int rt = 0; rt < 4; ++rt)
        ah[rt] = readfrag(lp, wr * 64 + rt * 16 + ql, kk, g);
#pragma unroll
      for (int ct = 0; ct < 4; ++ct)
        bh[ct] = readfrag(lk, wc * 64 + ct * 16 + ql, kk, g);
#pragma unroll
      for (int rt = 0; rt < 4; ++rt)
#pragma unroll
        for (int ct = 0; ct < 4; ++ct)
          acc[rt][ct] = mfma_(ah[rt], bh[ct], acc[rt][ct]);
    }
  }

  // epilogue: row = q, col = k; probs[b][q][k] = exp(E*INVT); l[q] += sums
#pragma unroll
  for (int rt = 0; rt < 4; ++rt) {
    float lpart[4] = {0.f, 0.f, 0.f, 0.f};
    int qb_ = q0 + wr * 64 + rt * 16 + g * 4;
#pragma unroll
    for (int ct = 0; ct < 4; ++ct) {
      int kcol = k0 + wc * 64 + ct * 16 + ql;
#pragma unroll
      for (int r = 0; r < 4; ++r) {
        float p = __expf(acc[rt][ct][r] * INVT);
        probs[((size_t)b * 2048 + qb_ + r) * 2048 + kcol] = f2bf(p);
        lpart[r] += p;
      }
    }
#pragma unroll
    for (int r = 0; r < 4; ++r) {
      float s = lpart[r];
      s += __shfl_xor(s, 1);
      s += __shfl_xor(s, 2);
      s += __shfl_xor(s, 4);
      s += __shfl_xor(s, 8);
      if (ql == 0) atomicAdd(&l[b * 2048 + qb_ + r], s);
    }
  }
}

// ---------------------------------------------------------------------------
// K4: output GEMM. outT[d][q] = sum_k ut[d][k] probs[q][k]; store out[q][d]/l.
// Grid 256: batch -> XCD pair.
__global__ __launch_bounds__(256, 2) void k_out(
    const u16* __restrict__ ut, const u16* __restrict__ probs,
    const float* __restrict__ l, float* __restrict__ out) {
  __shared__ u16 lu[8192], lq[8192];
  const int blk = blockIdx.x;
  const int xcd = blk & 7, half = xcd & 1, b = xcd >> 1;
  const int idx = blk >> 3;                  // 0..31
  const int dtb = half * 2 + (idx >> 4);     // 0..3
  const int qtb = idx & 15;                  // 0..15
  const int d0 = dtb * 128, q0 = qtb * 128;
  const int t = threadIdx.x, lane = t & 63, w = t >> 6;
  const int wr = w >> 1, wc = w & 1, ql = lane & 15, g = lane >> 4;
  const f4 fzero = {0.f, 0.f, 0.f, 0.f};
  f4 acc[4][4];
#pragma unroll
  for (int i = 0; i < 4; ++i)
#pragma unroll
    for (int j = 0; j < 4; ++j) acc[i][j] = fzero;

  for (int ks = 0; ks < 32; ++ks) {          // Kd = 2048
    __syncthreads();
    stage_tile(&ut[((size_t)b * 512 + d0) * 2048 + ks * 64], 2048, lu, t);
    stage_tile(&probs[((size_t)b * 2048 + q0) * 2048 + ks * 64], 2048, lq, t);
    __syncthreads();
#pragma unroll
    for (int kk = 0; kk < 2; ++kk) {
      b16x8 ah[4], bh[4];
#pragma unroll
      for (int rt = 0; rt < 4; ++rt)
        ah[rt] = readfrag(lu, wr * 64 + rt * 16 + ql, kk, g);
#pragma unroll
      for (int ct = 0; ct < 4; ++ct)
        bh[ct] = readfrag(lq, wc * 64 + ct * 16 + ql, kk, g);
#pragma unroll
      for (int rt = 0; rt < 4; ++rt)
#pragma unroll
        for (int ct = 0; ct < 4; ++ct)
          acc[rt][ct] = mfma_(ah[rt], bh[ct], acc[rt][ct]);
    }
  }

  // epilogue: row = d, col = q; out[b][q][d] = v / l[q], float4 stores
#pragma unroll
  for (int ct = 0; ct < 4; ++ct) {
    int q = q0 + wc * 64 + ct * 16 + ql;
    float inv = 1.0f / l[b * 2048 + q];
    size_t orow = ((size_t)b * 2048 + q) * 512;
#pragma unroll
    for (int rt = 0; rt < 4; ++rt) {
      int d = d0 + wr * 64 + rt * 16 + g * 4;
      f4 v = acc[rt][ct] * inv;
      *(f4*)&out[orow + d] = v;
    }
  }
}

// ---------------------------------------------------------------------------
extern "C" void kernel_launch(void* const* d_in, const int* in_sizes, int n_in,
                              void* d_out, int out_size, void* d_ws, size_t ws_size,
                              hipStream_t stream) {
  const float* x = (const float*)d_in[0];
  const float* Wk = (const float*)d_in[1];
  const float* Wq = (const float*)d_in[2];
  const float* Wv = (const float*)d_in[3];
  const float* Wa = (const float*)d_in[4];
  const float* Wb = (const float*)d_in[5];
  float* out = (float*)d_out;

  char* ws = (char*)d_ws;
  size_t off = 0;
  auto alloc = [&](size_t bytes) -> void* {
    void* p = ws + off;
    off += (bytes + 255) & ~(size_t)255;
    return p;
  };
  u16* wh = (u16*)alloc(1536 * 1024 * 2);
  u16* xh = (u16*)alloc((size_t)8192 * 1024 * 2);
  u16* kh = (u16*)alloc((size_t)8192 * 512 * 2);
  u16* ph = (u16*)alloc((size_t)8192 * 512 * 2);
  u16* ut = (u16*)alloc((size_t)8192 * 512 * 2);
  u16* probs = (u16*)alloc((size_t)4 * 2048 * 2048 * 2);
  float* l = (float*)alloc(8192 * 4);
  // ~77.5 MB of workspace
  (void)ws_size; (void)in_sizes; (void)n_in; (void)out_size;

  hipMemsetAsync(l, 0, 8192 * 4, stream);
  hipLaunchKernelGGL(k_split_x, dim3(8192), dim3(256), 0, stream, x, xh);
  hipLaunchKernelGGL(k_fold, dim3(1024), dim3(256), 0, stream, Wk, Wq, Wv, Wa, Wb, wh);
  hipLaunchKernelGGL(k_proj, dim3(12, 64), dim3(256), 0, stream, xh, wh, kh, ph, ut);
  hipLaunchKernelGGL(k_score, dim3(1024), dim3(256), 0, stream, ph, kh, probs, l);
  hipLaunchKernelGGL(k_out, dim3(256), dim3(256), 0, stream, ut, probs, l, out);
}

// Round 6
// 135.074 us; speedup vs baseline: 1.8214x; 1.2037x over previous
//
#include <hip/hip_runtime.h>

// SelfAttention_33852932227207 — MI355X, round 6.
// e = x^T (Wq^T Wa Wk) x / sqrt(512);  out = softmax(e) @ (x (Wb Wv)^T).
// Round-6: kill the 66µs scalar k_fold (MfmaUtil=0, latency-bound).
//   k_prep: Wk->bf16 copy; hi/lo splits of Wb; LDS tile-transposes+splits of
//           Wa^T, Wq^T, Wv^T (all [.][512] row-major, hi+lo).
//   k_fold_mfma: Wp = WaT @ WqT^T, Wu = Wb @ WvT^T as bf16x3 MFMA GEMMs
//           (512x1024, K=512) using the round-5 stage_tile/readfrag structure.
// k_split_x / k_proj / k_score / k_out unchanged from round 5.

typedef __attribute__((ext_vector_type(8))) short b16x8;
typedef __attribute__((ext_vector_type(4))) float f4;
typedef unsigned short u16;

#define DEVINL __device__ __forceinline__

DEVINL u16 f2bf(float f) {               // fp32 -> bf16 RNE
  unsigned int u = __float_as_uint(f);
  u = u + 0x7FFFu + ((u >> 16) & 1u);
  return (u16)(u >> 16);
}
DEVINL float bf2f(u16 h) { return __uint_as_float(((unsigned int)h) << 16); }

DEVINL f4 mfma_(b16x8 a, b16x8 b, f4 c) {
  return __builtin_amdgcn_mfma_f32_16x16x32_bf16(a, b, c, 0, 0, 0);
}
// bf16x3: (ah+al)*(bh+bl) ~= ah*bh + ah*bl + al*bh (al*bl dropped, ~2^-18 rel)
DEVINL f4 mfma3(b16x8 ah, b16x8 al, b16x8 bh, b16x8 bl, f4 c) {
  c = mfma_(ah, bh, c);
  c = mfma_(ah, bl, c);
  c = mfma_(al, bh, c);
  return c;
}
DEVINL void gload16(const u16* g, u16* l) {
  __builtin_amdgcn_global_load_lds(
      (const __attribute__((address_space(1))) void*)g,
      (__attribute__((address_space(3))) void*)l, 16, 0, 0);
}

// ---- shared GEMM tile helpers: [128][64] bf16 tile, 16B-chunk XOR swizzle.
DEVINL void stage_tile(const u16* __restrict__ gbase, int rstride,
                       u16* __restrict__ lds, int t) {
#pragma unroll
  for (int r = 0; r < 4; ++r) {
    int cp = r * 256 + t;                // chunk 0..1023
    int row = cp >> 3, j = cp & 7;
    int jj = j ^ (row & 7);
    gload16(&gbase[(size_t)row * rstride + jj * 8], &lds[cp * 8]);
  }
}
DEVINL b16x8 readfrag(const u16* __restrict__ lds, int row, int kk, int g) {
  int chunk = row * 8 + ((kk * 4 + g) ^ (row & 7));
  return *(const b16x8*)&lds[chunk * 8];
}

// ---------------------------------------------------------------------------
// K0: x [8192][1024] fp32 -> bf16
__global__ __launch_bounds__(256) void k_split_x(const float* __restrict__ x,
                                                 u16* __restrict__ xh) {
  int i = blockIdx.x * 256 + threadIdx.x;
  float4 v = ((const float4*)x)[i];
  ushort4 h;
  h.x = f2bf(v.x); h.y = f2bf(v.y); h.z = f2bf(v.z); h.w = f2bf(v.w);
  ((ushort4*)xh)[i] = h;
}

// ---------------------------------------------------------------------------
// K1: prep. blocks 0..511: Wk->wh rows 0..511 (hi). 512..767: Wb hi/lo split.
// 768..1087: 64x64 LDS tile transpose+split of Wa^T(64t), Wq^T(128t), Wv^T(128t).
__global__ __launch_bounds__(256) void k_prep(
    const float* __restrict__ Wk, const float* __restrict__ Wq,
    const float* __restrict__ Wv, const float* __restrict__ Wa,
    const float* __restrict__ Wb, u16* __restrict__ wh,
    u16* __restrict__ waT_h, u16* __restrict__ waT_l,
    u16* __restrict__ wqT_h, u16* __restrict__ wqT_l,
    u16* __restrict__ wb_h, u16* __restrict__ wb_l,
    u16* __restrict__ wvT_h, u16* __restrict__ wvT_l) {
  const int bid = blockIdx.x, t = threadIdx.x;
  if (bid < 512) {                       // Wk copy-split (hi only)
    int i = bid * 256 + t;
    float4 v = ((const float4*)Wk)[i];
    ushort4 h;
    h.x = f2bf(v.x); h.y = f2bf(v.y); h.z = f2bf(v.z); h.w = f2bf(v.w);
    ((ushort4*)wh)[i] = h;
    return;
  }
  if (bid < 768) {                       // Wb hi/lo split (no transpose)
    int i = (bid - 512) * 256 + t;       // float4 over 512*512/4 = 65536
    float4 v = ((const float4*)Wb)[i];
    ushort4 h, l;
    h.x = f2bf(v.x); l.x = f2bf(v.x - bf2f(h.x));
    h.y = f2bf(v.y); l.y = f2bf(v.y - bf2f(h.y));
    h.z = f2bf(v.z); l.z = f2bf(v.z - bf2f(h.z));
    h.w = f2bf(v.w); l.w = f2bf(v.w - bf2f(h.w));
    ((ushort4*)wb_h)[i] = h;
    ((ushort4*)wb_l)[i] = l;
    return;
  }
  // ---- 64x64 tile transpose + hi/lo split
  __shared__ float ftile[64][68];
  const int tb = bid - 768;              // 0..319
  const float* src;
  u16 *dh, *dl;
  int S, m0, c0;
  if (tb < 64) {                         // Wa [512][512] -> waT [512][512]
    src = Wa; dh = waT_h; dl = waT_l; S = 512;
    m0 = (tb >> 3) * 64; c0 = (tb & 7) * 64;
  } else if (tb < 192) {                 // Wq [512][1024] -> wqT [1024][512]
    int q = tb - 64;
    src = Wq; dh = wqT_h; dl = wqT_l; S = 1024;
    m0 = (q >> 4) * 64; c0 = (q & 15) * 64;
  } else {                               // Wv [512][1024] -> wvT [1024][512]
    int q = tb - 192;
    src = Wv; dh = wvT_h; dl = wvT_l; S = 1024;
    m0 = (q >> 4) * 64; c0 = (q & 15) * 64;
  }
  {
    int i = t >> 4, j4 = (t & 15) * 4;
#pragma unroll
    for (int ii = 0; ii < 4; ++ii) {
      int row = i + ii * 16;
      float4 v = *(const float4*)&src[(size_t)(m0 + row) * S + c0 + j4];
      ftile[row][j4] = v.x; ftile[row][j4 + 1] = v.y;
      ftile[row][j4 + 2] = v.z; ftile[row][j4 + 3] = v.w;
    }
  }
  __syncthreads();
  {
    int oc = t >> 2, mc = (t & 3) * 16;
#pragma unroll
    for (int j = 0; j < 4; ++j) {
      int m = mc + j * 4;
      float v0 = ftile[m][oc], v1 = ftile[m + 1][oc];
      float v2 = ftile[m + 2][oc], v3 = ftile[m + 3][oc];
      ushort4 h, l;
      h.x = f2bf(v0); l.x = f2bf(v0 - bf2f(h.x));
      h.y = f2bf(v1); l.y = f2bf(v1 - bf2f(h.y));
      h.z = f2bf(v2); l.z = f2bf(v2 - bf2f(h.z));
      h.w = f2bf(v3); l.w = f2bf(v3 - bf2f(h.w));
      size_t o = (size_t)(c0 + oc) * 512 + m0 + m;
      *(ushort4*)&dh[o] = h;
      *(ushort4*)&dl[o] = l;
    }
  }
}

// ---------------------------------------------------------------------------
// K2: fold GEMMs, bf16x3. blocks 0..31: Wp = waT @ wqT^T -> wh rows 512..1023.
// blocks 32..63: Wu = wb @ wvT^T -> wh rows 1024..1535. M=512,N=1024,K=512.
__global__ __launch_bounds__(256, 2) void k_fold_mfma(
    const u16* __restrict__ waT_h, const u16* __restrict__ waT_l,
    const u16* __restrict__ wqT_h, const u16* __restrict__ wqT_l,
    const u16* __restrict__ wb_h, const u16* __restrict__ wb_l,
    const u16* __restrict__ wvT_h, const u16* __restrict__ wvT_l,
    u16* __restrict__ wh) {
  __shared__ u16 lah[8192], lal[8192], lbh[8192], lbl[8192];
  const int blk = blockIdx.x;            // 0..63
  const int which = blk >> 5;            // 0 = Wp, 1 = Wu
  const int idx = blk & 31;
  const int r0 = (idx >> 3) * 128, c0 = (idx & 7) * 128;
  const u16* Ah = which ? wb_h : waT_h;
  const u16* Al = which ? wb_l : waT_l;
  const u16* Bh = which ? wvT_h : wqT_h;
  const u16* Bl = which ? wvT_l : wqT_l;
  const int obase = which ? 1024 : 512;
  const int t = threadIdx.x, lane = t & 63, w = t >> 6;
  const int wr = w >> 1, wc = w & 1, ql = lane & 15, g = lane >> 4;
  const f4 fzero = {0.f, 0.f, 0.f, 0.f};
  f4 acc[4][4];
#pragma unroll
  for (int i = 0; i < 4; ++i)
#pragma unroll
    for (int j = 0; j < 4; ++j) acc[i][j] = fzero;

  for (int ks = 0; ks < 8; ++ks) {       // K = 512
    __syncthreads();
    stage_tile(&Ah[(size_t)r0 * 512 + ks * 64], 512, lah, t);
    stage_tile(&Al[(size_t)r0 * 512 + ks * 64], 512, lal, t);
    stage_tile(&Bh[(size_t)c0 * 512 + ks * 64], 512, lbh, t);
    stage_tile(&Bl[(size_t)c0 * 512 + ks * 64], 512, lbl, t);
    __syncthreads();
#pragma unroll
    for (int kk = 0; kk < 2; ++kk) {
      b16x8 ah[4], al[4], bh[4], bl[4];
#pragma unroll
      for (int rt = 0; rt < 4; ++rt) {
        ah[rt] = readfrag(lah, wr * 64 + rt * 16 + ql, kk, g);
        al[rt] = readfrag(lal, wr * 64 + rt * 16 + ql, kk, g);
      }
#pragma unroll
      for (int ct = 0; ct < 4; ++ct) {
        bh[ct] = readfrag(lbh, wc * 64 + ct * 16 + ql, kk, g);
        bl[ct] = readfrag(lbl, wc * 64 + ct * 16 + ql, kk, g);
      }
#pragma unroll
      for (int rt = 0; rt < 4; ++rt)
#pragma unroll
        for (int ct = 0; ct < 4; ++ct)
          acc[rt][ct] = mfma3(ah[rt], al[rt], bh[ct], bl[ct], acc[rt][ct]);
    }
  }
  // epilogue: C frag col=lane&15, row=(lane>>4)*4+reg
#pragma unroll
  for (int rt = 0; rt < 4; ++rt) {
#pragma unroll
    for (int ct = 0; ct < 4; ++ct) {
      f4 v = acc[rt][ct];
      int col = c0 + wc * 64 + ct * 16 + ql;
      int rowb = r0 + wr * 64 + rt * 16 + g * 4;
#pragma unroll
      for (int r = 0; r < 4; ++r)
        wh[(size_t)(obase + rowb + r) * 1024 + col] = f2bf(v[r]);
    }
  }
}

// ---------------------------------------------------------------------------
// K3: projection GEMM  Y[8192][1536] = x[8192][1024] @ Wcat^T, bf16, BK=64.
__global__ __launch_bounds__(256, 2) void k_proj(
    const u16* __restrict__ xh, const u16* __restrict__ wh,
    u16* __restrict__ kh, u16* __restrict__ ph, u16* __restrict__ ut) {
  __shared__ u16 lxh[8192], lwh[8192];  // [128][64] each
  const int cb = blockIdx.x;   // 0..11 column block
  const int rb = blockIdx.y;   // 0..63 row block
  const int t = threadIdx.x, lane = t & 63, w = t >> 6;
  const int wr = w >> 1, wc = w & 1, ql = lane & 15, g = lane >> 4;
  const f4 fzero = {0.f, 0.f, 0.f, 0.f};
  f4 acc[4][4];
#pragma unroll
  for (int i = 0; i < 4; ++i)
#pragma unroll
    for (int j = 0; j < 4; ++j) acc[i][j] = fzero;

  for (int ks = 0; ks < 16; ++ks) {
    __syncthreads();
    stage_tile(&xh[(size_t)(rb * 128) * 1024 + ks * 64], 1024, lxh, t);
    stage_tile(&wh[(size_t)(cb * 128) * 1024 + ks * 64], 1024, lwh, t);
    __syncthreads();
#pragma unroll
    for (int kk = 0; kk < 2; ++kk) {
      b16x8 ah[4], bh[4];
#pragma unroll
      for (int rt = 0; rt < 4; ++rt)
        ah[rt] = readfrag(lxh, wr * 64 + rt * 16 + ql, kk, g);
#pragma unroll
      for (int ct = 0; ct < 4; ++ct)
        bh[ct] = readfrag(lwh, wc * 64 + ct * 16 + ql, kk, g);
#pragma unroll
      for (int rt = 0; rt < 4; ++rt)
#pragma unroll
        for (int ct = 0; ct < 4; ++ct)
          acc[rt][ct] = mfma_(ah[rt], bh[ct], acc[rt][ct]);
    }
  }

  // epilogue: C frag layout col=lane&15, row=(lane>>4)*4+reg
#pragma unroll
  for (int rt = 0; rt < 4; ++rt) {
#pragma unroll
    for (int ct = 0; ct < 4; ++ct) {
      f4 v = acc[rt][ct];
      int col = cb * 128 + wc * 64 + ct * 16 + ql;
      int rowb = rb * 128 + wr * 64 + rt * 16 + g * 4;
      if (cb < 4) {
#pragma unroll
        for (int r = 0; r < 4; ++r) kh[(size_t)(rowb + r) * 512 + col] = f2bf(v[r]);
      } else if (cb < 8) {
        int c2 = col - 512;
#pragma unroll
        for (int r = 0; r < 4; ++r) ph[(size_t)(rowb + r) * 512 + c2] = f2bf(v[r]);
      } else {
        int d = (cb - 8) * 128 + wc * 64 + ct * 16 + ql;
        int bb = rowb >> 11, k0 = rowb & 2047;
        ushort4 hh;
        hh.x = f2bf(v[0]); hh.y = f2bf(v[1]); hh.z = f2bf(v[2]); hh.w = f2bf(v[3]);
        *(ushort4*)&ut[((size_t)bb * 512 + d) * 2048 + k0] = hh;
      }
    }
  }
}

// ---------------------------------------------------------------------------
// K4: score GEMM. E[q][k] = sum_d P[q][d] K[k][d] per batch; epilogue
// probs = exp(E/T) bf16 + atomicAdd row sums l[b*2048+q].
__global__ __launch_bounds__(256, 2) void k_score(
    const u16* __restrict__ ph, const u16* __restrict__ kh,
    u16* __restrict__ probs, float* __restrict__ l) {
  constexpr float INVT = 0.04419417382415922f;  // 1/sqrt(512)
  __shared__ u16 lp[8192], lk[8192];
  const int blk = blockIdx.x;
  const int xcd = blk & 7, half = xcd & 1, b = xcd >> 1;
  const int idx = blk >> 3;                  // 0..127
  const int qtb = idx >> 3;                  // 0..15
  const int ktb = half * 8 + (idx & 7);      // 0..15
  const int q0 = qtb * 128, k0 = ktb * 128;
  const int t = threadIdx.x, lane = t & 63, w = t >> 6;
  const int wr = w >> 1, wc = w & 1, ql = lane & 15, g = lane >> 4;
  const f4 fzero = {0.f, 0.f, 0.f, 0.f};
  f4 acc[4][4];
#pragma unroll
  for (int i = 0; i < 4; ++i)
#pragma unroll
    for (int j = 0; j < 4; ++j) acc[i][j] = fzero;

  for (int ks = 0; ks < 8; ++ks) {           // Kd = 512
    __syncthreads();
    stage_tile(&ph[((size_t)b * 2048 + q0) * 512 + ks * 64], 512, lp, t);
    stage_tile(&kh[((size_t)b * 2048 + k0) * 512 + ks * 64], 512, lk, t);
    __syncthreads();
#pragma unroll
    for (int kk = 0; kk < 2; ++kk) {
      b16x8 ah[4], bh[4];
#pragma unroll
      for (int rt = 0; rt < 4; ++rt)
        ah[rt] = readfrag(lp, wr * 64 + rt * 16 + ql, kk, g);
#pragma unroll
      for (int ct = 0; ct < 4; ++ct)
        bh[ct] = readfrag(lk, wc * 64 + ct * 16 + ql, kk, g);
#pragma unroll
      for (int rt = 0; rt < 4; ++rt)
#pragma unroll
        for (int ct = 0; ct < 4; ++ct)
          acc[rt][ct] = mfma_(ah[rt], bh[ct], acc[rt][ct]);
    }
  }

  // epilogue: probs[b][q][k] = exp(E*INVT); l[q] += sums
#pragma unroll
  for (int rt = 0; rt < 4; ++rt) {
    float lpart[4] = {0.f, 0.f, 0.f, 0.f};
    int qb_ = q0 + wr * 64 + rt * 16 + g * 4;
#pragma unroll
    for (int ct = 0; ct < 4; ++ct) {
      int kcol = k0 + wc * 64 + ct * 16 + ql;
#pragma unroll
      for (int r = 0; r < 4; ++r) {
        float p = __expf(acc[rt][ct][r] * INVT);
        probs[((size_t)b * 2048 + qb_ + r) * 2048 + kcol] = f2bf(p);
        lpart[r] += p;
      }
    }
#pragma unroll
    for (int r = 0; r < 4; ++r) {
      float s = lpart[r];
      s += __shfl_xor(s, 1);
      s += __shfl_xor(s, 2);
      s += __shfl_xor(s, 4);
      s += __shfl_xor(s, 8);
      if (ql == 0) atomicAdd(&l[b * 2048 + qb_ + r], s);
    }
  }
}

// ---------------------------------------------------------------------------
// K5: output GEMM. outT[d][q] = sum_k ut[d][k] probs[q][k]; store out[q][d]/l.
__global__ __launch_bounds__(256, 2) void k_out(
    const u16* __restrict__ ut, const u16* __restrict__ probs,
    const float* __restrict__ l, float* __restrict__ out) {
  __shared__ u16 lu[8192], lq[8192];
  const int blk = blockIdx.x;
  const int xcd = blk & 7, half = xcd & 1, b = xcd >> 1;
  const int idx = blk >> 3;                  // 0..31
  const int dtb = half * 2 + (idx >> 4);     // 0..3
  const int qtb = idx & 15;                  // 0..15
  const int d0 = dtb * 128, q0 = qtb * 128;
  const int t = threadIdx.x, lane = t & 63, w = t >> 6;
  const int wr = w >> 1, wc = w & 1, ql = lane & 15, g = lane >> 4;
  const f4 fzero = {0.f, 0.f, 0.f, 0.f};
  f4 acc[4][4];
#pragma unroll
  for (int i = 0; i < 4; ++i)
#pragma unroll
    for (int j = 0; j < 4; ++j) acc[i][j] = fzero;

  for (int ks = 0; ks < 32; ++ks) {          // Kd = 2048
    __syncthreads();
    stage_tile(&ut[((size_t)b * 512 + d0) * 2048 + ks * 64], 2048, lu, t);
    stage_tile(&probs[((size_t)b * 2048 + q0) * 2048 + ks * 64], 2048, lq, t);
    __syncthreads();
#pragma unroll
    for (int kk = 0; kk < 2; ++kk) {
      b16x8 ah[4], bh[4];
#pragma unroll
      for (int rt = 0; rt < 4; ++rt)
        ah[rt] = readfrag(lu, wr * 64 + rt * 16 + ql, kk, g);
#pragma unroll
      for (int ct = 0; ct < 4; ++ct)
        bh[ct] = readfrag(lq, wc * 64 + ct * 16 + ql, kk, g);
#pragma unroll
      for (int rt = 0; rt < 4; ++rt)
#pragma unroll
        for (int ct = 0; ct < 4; ++ct)
          acc[rt][ct] = mfma_(ah[rt], bh[ct], acc[rt][ct]);
    }
  }

  // epilogue: row = d, col = q; out[b][q][d] = v / l[q], float4 stores
#pragma unroll
  for (int ct = 0; ct < 4; ++ct) {
    int q = q0 + wc * 64 + ct * 16 + ql;
    float inv = 1.0f / l[b * 2048 + q];
    size_t orow = ((size_t)b * 2048 + q) * 512;
#pragma unroll
    for (int rt = 0; rt < 4; ++rt) {
      int d = d0 + wr * 64 + rt * 16 + g * 4;
      f4 v = acc[rt][ct] * inv;
      *(f4*)&out[orow + d] = v;
    }
  }
}

// ---------------------------------------------------------------------------
extern "C" void kernel_launch(void* const* d_in, const int* in_sizes, int n_in,
                              void* d_out, int out_size, void* d_ws, size_t ws_size,
                              hipStream_t stream) {
  const float* x = (const float*)d_in[0];
  const float* Wk = (const float*)d_in[1];
  const float* Wq = (const float*)d_in[2];
  const float* Wv = (const float*)d_in[3];
  const float* Wa = (const float*)d_in[4];
  const float* Wb = (const float*)d_in[5];
  float* out = (float*)d_out;

  char* ws = (char*)d_ws;
  size_t off = 0;
  auto alloc = [&](size_t bytes) -> void* {
    void* p = ws + off;
    off += (bytes + 255) & ~(size_t)255;
    return p;
  };
  u16* wh = (u16*)alloc((size_t)1536 * 1024 * 2);
  u16* xh = (u16*)alloc((size_t)8192 * 1024 * 2);
  u16* kh = (u16*)alloc((size_t)8192 * 512 * 2);
  u16* ph = (u16*)alloc((size_t)8192 * 512 * 2);
  u16* ut = (u16*)alloc((size_t)8192 * 512 * 2);
  u16* probs = (u16*)alloc((size_t)4 * 2048 * 2048 * 2);
  float* l = (float*)alloc(8192 * 4);
  u16* waT_h = (u16*)alloc((size_t)512 * 512 * 2);
  u16* waT_l = (u16*)alloc((size_t)512 * 512 * 2);
  u16* wqT_h = (u16*)alloc((size_t)1024 * 512 * 2);
  u16* wqT_l = (u16*)alloc((size_t)1024 * 512 * 2);
  u16* wb_h = (u16*)alloc((size_t)512 * 512 * 2);
  u16* wb_l = (u16*)alloc((size_t)512 * 512 * 2);
  u16* wvT_h = (u16*)alloc((size_t)1024 * 512 * 2);
  u16* wvT_l = (u16*)alloc((size_t)1024 * 512 * 2);
  // ~84 MB of workspace
  (void)ws_size; (void)in_sizes; (void)n_in; (void)out_size;

  hipMemsetAsync(l, 0, 8192 * 4, stream);
  hipLaunchKernelGGL(k_split_x, dim3(8192), dim3(256), 0, stream, x, xh);
  hipLaunchKernelGGL(k_prep, dim3(1088), dim3(256), 0, stream,
                     Wk, Wq, Wv, Wa, Wb, wh,
                     waT_h, waT_l, wqT_h, wqT_l, wb_h, wb_l, wvT_h, wvT_l);
  hipLaunchKernelGGL(k_fold_mfma, dim3(64), dim3(256), 0, stream,
                     waT_h, waT_l, wqT_h, wqT_l, wb_h, wb_l, wvT_h, wvT_l, wh);
  hipLaunchKernelGGL(k_proj, dim3(12, 64), dim3(256), 0, stream, xh, wh, kh, ph, ut);
  hipLaunchKernelGGL(k_score, dim3(1024), dim3(256), 0, stream, ph, kh, probs, l);
  hipLaunchKernelGGL(k_out, dim3(256), dim3(256), 0, stream, ut, probs, l, out);
}